// Round 2
// baseline (508.741 us; speedup 1.0000x reference)
//
#include <hip/hip_runtime.h>
#include <hip/hip_bf16.h>

// GCN layer on MI355X.
//   pass 1 (gcn_prep): 32 rows/block: rowsum(adj)+1 -> dinv;
//                      yT[f][j] = bf16(dinv_j * x[j][f]) written as coalesced
//                      [128][32] tiles; tail blocks: Wb = bf16(W)
//   pass 2 (gcn_main): h0 = adj @ y  (bf16 MFMA, adj converted on the fly),
//                      M_TILE=16, BKC=256 -> 16KB LDS, 2 blocks/CU,
//                      XOR-swizzled LDS staging (kills 16-way ds_read conflict)
//                      t  = dinv_i*h0 + dinv_i^2*x   (self-loop term)
//                      z  = t @ W^T + b ; out = z / max(||z||_2, eps)
//
// ws layout: [0,2MB) yT (128x8192 bf16) | [2MB,+32KB) dinv f32 | +32KB Wb bf16

typedef __attribute__((ext_vector_type(8))) short short8;     // 8 x bf16 (4 VGPR)
typedef __attribute__((ext_vector_type(4))) float f32x4;      // MFMA acc
typedef __attribute__((ext_vector_type(4))) unsigned short us4;

static __device__ __forceinline__ unsigned short f2bf(float f) {
    // round-to-nearest-even bf16
    unsigned int u = __float_as_uint(f);
    u += 0x7FFFu + ((u >> 16) & 1u);
    return (unsigned short)(u >> 16);
}

// ---------------------------------------------------------------- pass 1 ----
// grid: 256 row-blocks (32 rows each) + 32 tail blocks (W -> bf16), 512 thr
__global__ __launch_bounds__(512) void gcn_prep(
    const float* __restrict__ adj, const float* __restrict__ x,
    const float* __restrict__ W,
    unsigned short* __restrict__ yT, float* __restrict__ dinv,
    unsigned short* __restrict__ Wb)
{
    const int tid = threadIdx.x;
    const int blk = blockIdx.x;
    if (blk >= 256) {                       // tail: convert W -> bf16
        int idx = (blk - 256) * 512 + tid;  // 32 blocks * 512 = 16384 = 128*128
        Wb[idx] = f2bf(W[idx]);
        return;
    }
    const int wave = tid >> 6;
    const int lane = tid & 63;
    const long j0 = (long)blk * 32;

    __shared__ float s_di[32];

    // rowsums: wave w owns rows j0 + 4w .. j0 + 4w+3 (8 waves x 4 rows = 32)
    for (int r = 0; r < 4; ++r) {
        const long j = j0 + wave * 4 + r;
        const float4* row = (const float4*)(adj + j * 8192L);
        float s = 0.f;
#pragma unroll
        for (int it = 0; it < 32; ++it) {   // 64 lanes * 32 it * 4 = 8192 floats
            float4 v = row[it * 64 + lane];
            s += (v.x + v.y) + (v.z + v.w);
        }
        for (int off = 1; off < 64; off <<= 1) s += __shfl_xor(s, off, 64);
        if (lane == 0) s_di[wave * 4 + r] = rsqrtf(s + 1.0f);  // +1: self loop
    }
    __syncthreads();
    if (tid < 32) dinv[j0 + tid] = s_di[tid];

    // transposed write, fully coalesced: 32 consecutive threads write one
    // 64B line yT[f][j0..j0+31]. thread t -> jj = t&31, f = p*16 + (t>>5)
    const int jj = tid & 31;
    const int fb = tid >> 5;                // 0..15
    const float di = s_di[jj];
#pragma unroll
    for (int p = 0; p < 8; ++p) {
        int f = p * 16 + fb;
        yT[(long)f * 8192 + j0 + jj] = f2bf(di * x[(j0 + jj) * 128 + f]);
    }
}

// ---------------------------------------------------------------- pass 2 ----
#define M_TILE 16
#define BKC    256           // K per chunk
#define NCHUNK 32            // 8192 / 256

// XOR swizzle (units: shorts). Row stride 256 shorts = 512B; without the XOR
// all 16 lanes of a quad land in the same 16B bank slot (16-way conflict).
// XOR of bits 3..5 (16/32/64B) spreads rows across 8 slots = b128 BW floor,
// and preserves both 8B (us4 write) and 16B (short8 read) alignment.
#define SWZ(r, c) ((r) * BKC + ((c) ^ (((r) & 7) << 3)))

// 512 threads = 8 waves. Wave w owns output cols w*16..w*16+15, rows 0..15.
// 16KB LDS total -> 2 blocks/CU (4 waves/SIMD).
__global__ __launch_bounds__(512, 4) void gcn_main(
    const float* __restrict__ adj, const float* __restrict__ x,
    const float* __restrict__ bias,
    const unsigned short* __restrict__ yT, const float* __restrict__ dinv,
    const unsigned short* __restrict__ Wb, float* __restrict__ out)
{
    __shared__ unsigned short Ab[2][M_TILE * BKC];   // 2 x 8KB = 16KB

    const int tid  = threadIdx.x;
    const int wave = tid >> 6;        // 0..7
    const int lane = tid & 63;
    const int q    = lane >> 4;       // quad 0..3 (k-chunk select)
    const int ln   = lane & 15;
    const int nb   = wave * 16;       // this wave's 16-col N slice
    const long rowBase = (long)blockIdx.x * M_TILE;

    f32x4 acc = {};                   // 16 rows x 16 cols per wave
    float4 st[2];                     // staged fp32 adj (2KB/wave per chunk)

    // chunk = [16 rows][256 k] fp32 = 16KB. One wave covers one row per instr.
    auto load_chunk = [&](int c) {
#pragma unroll
        for (int i = 0; i < 2; ++i) {
            int row = wave + i * 8;
            st[i] = *(const float4*)&adj[(rowBase + row) * 8192L + (long)c * BKC + lane * 4];
        }
    };
    auto write_chunk = [&](int buf) {
#pragma unroll
        for (int i = 0; i < 2; ++i) {
            int row = wave + i * 8;
            us4 w4;
            w4.x = f2bf(st[i].x); w4.y = f2bf(st[i].y);
            w4.z = f2bf(st[i].z); w4.w = f2bf(st[i].w);
            *(us4*)&Ab[buf][SWZ(row, lane * 4)] = w4;
        }
    };

    load_chunk(0);
    write_chunk(0);
    __syncthreads();

#pragma unroll 1
    for (int c = 0; c < NCHUNK; ++c) {
        const int cur = c & 1;
        if (c + 1 < NCHUNK) load_chunk(c + 1);      // in flight during compute
#pragma unroll
        for (int s = 0; s < BKC / 32; ++s) {        // 8 K-steps of 32
            const int k0 = s * 32 + q * 8;
            short8 a = *(const short8*)&Ab[cur][SWZ(ln, k0)];
            short8 b = *(const short8*)&yT[(nb + ln) * 8192L + (long)c * BKC + k0];
            acc = __builtin_amdgcn_mfma_f32_16x16x32_bf16(a, b, acc, 0, 0, 0);
        }
        if (c + 1 < NCHUNK) write_chunk(cur ^ 1);   // waitcnt lands here, after compute
        __syncthreads();
    }

    // ---- fused epilogue (scratch overlays Ab[0]; last compute read Ab[1]) ----
    unsigned short* t_lds = &Ab[0][0];              // [16][136] bf16 (pad 8)
    float* s_dinv = (float*)(t_lds + 16 * 136);
    float* s_part = s_dinv + 16;                    // [16][8] per-wave |z|^2
    float* s_inv  = s_part + 128;                   // [16]

    if (tid < 16) s_dinv[tid] = dinv[rowBase + tid];
    __syncthreads();

    // t = dinv_i * (adj@y)_i + dinv_i^2 * x_i  -> LDS (bf16)
#pragma unroll
    for (int r = 0; r < 4; ++r) {
        int m = q * 4 + r;
        int n = nb + ln;
        float di = s_dinv[m];
        float tv = di * acc[r] + di * di * x[(rowBase + m) * 128 + n];
        t_lds[m * 136 + n] = f2bf(tv);
    }
    __syncthreads();

    // z = t @ W^T via MFMA (B = Wb rows are contiguous in k)
    f32x4 z = {};
#pragma unroll
    for (int s = 0; s < 4; ++s) {
        const int k0 = s * 32 + q * 8;
        short8 a = *(const short8*)&t_lds[ln * 136 + k0];
        short8 b = *(const short8*)&Wb[(nb + ln) * 128 + k0];
        z = __builtin_amdgcn_mfma_f32_16x16x32_bf16(a, b, z, 0, 0, 0);
    }

    // + bias, accumulate |z|^2 per row (this wave's 16 cols)
    float bv = bias[nb + ln];
    float zv[4], rp[4];
#pragma unroll
    for (int r = 0; r < 4; ++r) {
        float v = z[r] + bv;
        zv[r] = v;
        rp[r] = v * v;
    }
#pragma unroll
    for (int r = 0; r < 4; ++r)
        for (int off = 1; off < 16; off <<= 1)
            rp[r] += __shfl_xor(rp[r], off, 64);    // reduce over 16 n-lanes
    if (ln == 0) {
#pragma unroll
        for (int r = 0; r < 4; ++r)
            s_part[(q * 4 + r) * 8 + wave] = rp[r];
    }
    __syncthreads();
    if (tid < 16) {
        float s = 0.f;
#pragma unroll
        for (int w = 0; w < 8; ++w) s += s_part[tid * 8 + w];
        float nrm = sqrtf(s);
        s_inv[tid] = 1.0f / fmaxf(nrm, 1e-12f);     // F.normalize eps
    }
    __syncthreads();

#pragma unroll
    for (int r = 0; r < 4; ++r) {
        int m = q * 4 + r;
        out[(rowBase + m) * 128 + nb + ln] = zv[r] * s_inv[m];
    }
}

// ---------------------------------------------------------------- launch ----
extern "C" void kernel_launch(void* const* d_in, const int* in_sizes, int n_in,
                              void* d_out, int out_size, void* d_ws, size_t ws_size,
                              hipStream_t stream) {
    const float* x   = (const float*)d_in[0];   // [8192,128]
    const float* adj = (const float*)d_in[1];   // [8192,8192]
    const float* W   = (const float*)d_in[2];   // [128,128]
    const float* b   = (const float*)d_in[3];   // [128]
    float* out = (float*)d_out;

    unsigned short* yT  = (unsigned short*)d_ws;                         // 2 MB
    float*          dv  = (float*)((char*)d_ws + (2u << 20));            // 32 KB
    unsigned short* Wb  = (unsigned short*)((char*)d_ws + (2u << 20) + 32768);

    gcn_prep<<<256 + 32, 512, 0, stream>>>(adj, x, W, yT, dv, Wb);
    gcn_main<<<512, 512, 0, stream>>>(adj, x, b, yT, dv, Wb, out);
}

// Round 3
// 459.353 us; speedup vs baseline: 1.1075x; 1.1075x over previous
//
#include <hip/hip_runtime.h>
#include <hip/hip_bf16.h>

// GCN layer on MI355X, v3: convert-once + fragment-packed adjb.
//   pass 1 (gcn_prep): rowsum(adj)+1 -> dinv; adjb = bf16(adj) stored in
//                      MFMA-fragment order [rt][ks][lane][8] (full-line
//                      coalesced writes); yT[f][j] = bf16(dinv_j * x[j][f]);
//                      tail blocks: Wb = bf16(W)
//   pass 2 (gcn_main): pure bf16 GEMM h0 = adjb @ y. A-fragments streamed
//                      HBM->LDS via global_load_lds width=16 (packed layout
//                      is linear lane-major -> no swizzle, conflict-free
//                      ds_read at lane*16). Per wave: 16 unique cols, both
//                      row-tiles. Fused epilogue: t = dinv*h0 + dinv^2*x;
//                      z = t @ W^T + b ; out = z / max(||z||,eps)
//
// ws: [0,2MB) yT | [2MB,+128B..) dinv | +32KB Wb | [4MB,+128MB) adjb packed

typedef __attribute__((ext_vector_type(8))) short short8;     // 8 x bf16
typedef __attribute__((ext_vector_type(4))) float f32x4;      // MFMA acc
typedef __attribute__((ext_vector_type(4))) unsigned short us4;

static __device__ __forceinline__ unsigned short f2bf(float f) {
    unsigned int u = __float_as_uint(f);
    u += 0x7FFFu + ((u >> 16) & 1u);
    return (unsigned short)(u >> 16);
}

static __device__ __forceinline__ void gload16(const void* g, const void* l) {
    __builtin_amdgcn_global_load_lds(
        (const __attribute__((address_space(1))) unsigned int*)g,
        (__attribute__((address_space(3))) unsigned int*)l, 16, 0, 0);
}

// ---------------------------------------------------------------- pass 1 ----
// 256 row-blocks (32 rows each, 8 waves x 4 rows, 16 lanes/row) + 32 W-blocks
__global__ __launch_bounds__(512) void gcn_prep(
    const float* __restrict__ adj, const float* __restrict__ x,
    const float* __restrict__ W,
    unsigned short* __restrict__ yT, float* __restrict__ dinv,
    unsigned short* __restrict__ Wb, unsigned short* __restrict__ adjb)
{
    const int tid = threadIdx.x;
    const int blk = blockIdx.x;
    if (blk >= 256) {                       // tail: convert W -> bf16
        int idx = (blk - 256) * 512 + tid;  // 32*512 = 16384 = 128*128
        Wb[idx] = f2bf(W[idx]);
        return;
    }
    const int wave   = tid >> 6;
    const int lane   = tid & 63;
    const int rowsel = lane >> 4;           // 4 rows per wave
    const int l16    = lane & 15;           // 16 lanes per row
    const long j0 = (long)blk * 32;
    const long j  = j0 + wave * 4 + rowsel; // rows 4-consecutive per wave:
    const int rt = (int)(j >> 4);           // packed writes form full 64B lines
    const int ln = (int)(j & 15);
    const int q  = (l16 >> 1) & 3;
    const int jj = (l16 & 1) * 4;

    __shared__ float s_di[32];

    const float4* rowp = (const float4*)(adj + j * 8192L);
    float s = 0.f;
#pragma unroll 8
    for (int it = 0; it < 128; ++it) {      // 16 lanes * 128 it * 4 = 8192
        float4 v = rowp[it * 16 + l16];
        s += (v.x + v.y) + (v.z + v.w);
        int ks = it * 2 + (l16 >> 3);       // k-step = (it*64 + l16*4) >> 5
        us4 w4;
        w4.x = f2bf(v.x); w4.y = f2bf(v.y);
        w4.z = f2bf(v.z); w4.w = f2bf(v.w);
        // packed: [rt][ks][lane'=q*16+ln][8 shorts]
        *(us4*)&adjb[(((long)rt * 256 + ks) * 64 + q * 16 + ln) * 8 + jj] = w4;
    }
    s += __shfl_xor(s, 1, 64);
    s += __shfl_xor(s, 2, 64);
    s += __shfl_xor(s, 4, 64);
    s += __shfl_xor(s, 8, 64);              // reduce within 16-lane group
    if (l16 == 0) s_di[wave * 4 + rowsel] = rsqrtf(s + 1.0f);  // +1 self loop
    __syncthreads();
    if (tid < 32) dinv[j0 + tid] = s_di[tid];

    // yT write, coalesced: 32 threads = one 64B line yT[f][j0..j0+31]
    const int jy = tid & 31;
    const int fb = tid >> 5;                // 0..15
    const float di = s_di[jy];
#pragma unroll
    for (int p = 0; p < 8; ++p) {
        int f = p * 16 + fb;
        yT[(long)f * 8192 + j0 + jy] = f2bf(di * x[(j0 + jy) * 128 + f]);
    }
}

// ---------------------------------------------------------------- pass 2 ----
#define CK 16                 // k-steps per chunk (16 x 32 = 512 k)
#define NCHUNK 16             // 8192 / 512

// 256 blocks x 512 thr (8 waves). Block: 32 rows (2 row-tiles) x 128 cols.
// Wave w: cols w*16..w*16+15 (unique -> B read once/block), both row-tiles.
__global__ __launch_bounds__(512) void gcn_main(
    const unsigned short* __restrict__ adjb, const float* __restrict__ x,
    const float* __restrict__ bias,
    const unsigned short* __restrict__ yT, const float* __restrict__ dinv,
    const unsigned short* __restrict__ Wb, float* __restrict__ out)
{
    __shared__ unsigned short AbS[2][32 * 512];   // 2 x 32KB (32 slots x 1KB)

    const int tid  = threadIdx.x;
    const int wave = tid >> 6;        // 0..7
    const int lane = tid & 63;
    const int q    = lane >> 4;
    const int ln   = lane & 15;
    const int blk  = blockIdx.x;
    const long rowBase = (long)blk * 32;

    f32x4 acc[2] = {};                // [rt] : 2x16 rows x 16 cols

    // stage one 32KB chunk (32 slots of 1KB); slot s = (rt*16 + ks)
    auto stage = [&](int c, int buf) {
#pragma unroll
        for (int i = 0; i < 4; ++i) {
            int s = i * 8 + wave;
            const char* src = (const char*)adjb +
                ((((long)(blk * 2 + (s >> 4))) * 256 + c * CK + (s & 15)) * 64 + lane) * 16;
            gload16(src, &AbS[buf][s * 512]);
        }
    };

    stage(0, 0);
    __syncthreads();

    const unsigned short* bcol = &yT[(wave * 16 + ln) * 8192L + q * 8];

#pragma unroll 1
    for (int c = 0; c < NCHUNK; ++c) {
        const int cur = c & 1;
        if (c + 1 < NCHUNK) stage(c + 1, cur ^ 1);   // fire-and-forget
#pragma unroll
        for (int ks = 0; ks < CK; ++ks) {
            short8 a0 = *(const short8*)&AbS[cur][ks * 512 + lane * 8];
            short8 a1 = *(const short8*)&AbS[cur][(16 + ks) * 512 + lane * 8];
            short8 b  = *(const short8*)&bcol[c * 512 + ks * 32];
            acc[0] = __builtin_amdgcn_mfma_f32_16x16x32_bf16(a0, b, acc[0], 0, 0, 0);
            acc[1] = __builtin_amdgcn_mfma_f32_16x16x32_bf16(a1, b, acc[1], 0, 0, 0);
        }
        __syncthreads();       // staged loads landed; buffers safe to flip
    }

    // ---- fused epilogue (scratch overlays AbS[0]; last compute read AbS[1])
    unsigned short* t_lds = &AbS[0][0];             // [32][136] bf16 (pad 8)
    float* s_dinv = (float*)(t_lds + 32 * 136);
    float* s_part = s_dinv + 32;                    // [32][8] per-wave |z|^2
    float* s_inv  = s_part + 256;                   // [32]

    if (tid < 32) s_dinv[tid] = dinv[rowBase + tid];
    __syncthreads();

    // t = dinv_i * (adj@y)_i + dinv_i^2 * x_i  -> LDS (bf16)
#pragma unroll
    for (int rt = 0; rt < 2; ++rt)
#pragma unroll
        for (int r = 0; r < 4; ++r) {
            int m = rt * 16 + q * 4 + r;
            int n = wave * 16 + ln;
            float di = s_dinv[m];
            float tv = di * acc[rt][r] + di * di * x[(rowBase + m) * 128 + n];
            t_lds[m * 136 + n] = f2bf(tv);
        }
    __syncthreads();

    // z = t @ W^T via MFMA
    f32x4 z[2] = {};
#pragma unroll
    for (int s = 0; s < 4; ++s) {
        const int k0 = s * 32 + q * 8;
        short8 a0 = *(const short8*)&t_lds[ln * 136 + k0];
        short8 a1 = *(const short8*)&t_lds[(16 + ln) * 136 + k0];
        short8 b  = *(const short8*)&Wb[(wave * 16 + ln) * 128 + k0];
        z[0] = __builtin_amdgcn_mfma_f32_16x16x32_bf16(a0, b, z[0], 0, 0, 0);
        z[1] = __builtin_amdgcn_mfma_f32_16x16x32_bf16(a1, b, z[1], 0, 0, 0);
    }

    // + bias, |z|^2 partials over this wave's 16 cols
    float bv = bias[wave * 16 + ln];
    float zv[2][4], rp[2][4];
#pragma unroll
    for (int rt = 0; rt < 2; ++rt)
#pragma unroll
        for (int r = 0; r < 4; ++r) {
            float v = z[rt][r] + bv;
            zv[rt][r] = v;
            rp[rt][r] = v * v;
        }
#pragma unroll
    for (int rt = 0; rt < 2; ++rt)
#pragma unroll
        for (int r = 0; r < 4; ++r) {
            rp[rt][r] += __shfl_xor(rp[rt][r], 1, 64);
            rp[rt][r] += __shfl_xor(rp[rt][r], 2, 64);
            rp[rt][r] += __shfl_xor(rp[rt][r], 4, 64);
            rp[rt][r] += __shfl_xor(rp[rt][r], 8, 64);
        }
    if (ln == 0) {
#pragma unroll
        for (int rt = 0; rt < 2; ++rt)
#pragma unroll
            for (int r = 0; r < 4; ++r)
                s_part[(rt * 16 + q * 4 + r) * 8 + wave] = rp[rt][r];
    }
    __syncthreads();
    if (tid < 32) {
        float s = 0.f;
#pragma unroll
        for (int w = 0; w < 8; ++w) s += s_part[tid * 8 + w];
        s_inv[tid] = 1.0f / fmaxf(sqrtf(s), 1e-12f);   // F.normalize eps
    }
    __syncthreads();

#pragma unroll
    for (int rt = 0; rt < 2; ++rt)
#pragma unroll
        for (int r = 0; r < 4; ++r) {
            int m = rt * 16 + q * 4 + r;
            out[(rowBase + m) * 128 + wave * 16 + ln] = zv[rt][r] * s_inv[m];
        }
}

// ---------------------------------------------------------------- launch ----
extern "C" void kernel_launch(void* const* d_in, const int* in_sizes, int n_in,
                              void* d_out, int out_size, void* d_ws, size_t ws_size,
                              hipStream_t stream) {
    const float* x   = (const float*)d_in[0];   // [8192,128]
    const float* adj = (const float*)d_in[1];   // [8192,8192]
    const float* W   = (const float*)d_in[2];   // [128,128]
    const float* b   = (const float*)d_in[3];   // [128]
    float* out = (float*)d_out;

    unsigned short* yT   = (unsigned short*)d_ws;                          // 2MB
    float*          dv   = (float*)((char*)d_ws + (2u << 20));             // 128B
    unsigned short* Wb   = (unsigned short*)((char*)d_ws + (2u << 20) + 32768);
    unsigned short* adjb = (unsigned short*)((char*)d_ws + (4u << 20));    // 128MB

    gcn_prep<<<256 + 32, 512, 0, stream>>>(adj, x, W, yT, dv, Wb, adjb);
    gcn_main<<<256, 512, 0, stream>>>(adjb, x, b, yT, dv, Wb, out);
}